// Round 3
// baseline (89.000 us; speedup 1.0000x reference)
//
#include <hip/hip_runtime.h>
#include <hip/hip_bf16.h>

#define DD 512
#define NN 8
#define LL0 128
#define LL1 256

// 2 * log2(e): pre-scale factor so tanh(t) can use v_exp_f32 (2^x) directly.
#define LOG2E2 2.8853900817779268f

// split-K partial plane stride (floats): 3072 rows x 512 e
#define PSTR ((size_t)3072 * 512)

__device__ __forceinline__ float fexp2(float x) {
#if __has_builtin(__builtin_amdgcn_exp2f)
    return __builtin_amdgcn_exp2f(x);
#else
    float r; asm("v_exp_f32 %0, %1" : "=v"(r) : "v"(x)); return r;
#endif
}
__device__ __forceinline__ float frcp(float x) {
#if __has_builtin(__builtin_amdgcn_rcpf)
    return __builtin_amdgcn_rcpf(x);
#else
    float r; asm("v_rcp_f32 %0, %1" : "=v"(r) : "v"(x)); return r;
#endif
}

// sigma2(t2) = 1/(2^t2 + 1), where t2 = 2*log2e*t.  tanh(t) = 1 - 2*sigma2.
__device__ __forceinline__ float sig2(float t2) {
    return frcp(fexp2(t2) + 1.0f);
}

// ---------------------------------------------------------------------------
// Kernel 1: fused projections, split-K=4, 128x128 tile, 8x8 micro-tile.
// pp[kz][row][e] = sum_{k in quarter kz} A[row,k] * W[e, koff+k]
//   rows [0,1024)   : A = x, koff = 0
//   rows [1024,3072): A = m, koff = 512
// LDS tiles transposed [k][row] (pad 132); fragments split {c*4, 64+c*4} so
// ds_read_b128 is 2-way-conflict-free (free). Double-buffered: 1 barrier/tile.
// Grid (24, 4, 4) = 384 blocks. LDS = 2*2*32*132*4 = 67.6 KB -> 2 blocks/CU.
// ---------------------------------------------------------------------------
__global__ __launch_bounds__(256, 2) void proj_kernel(
    const float* __restrict__ x, const float* __restrict__ m,
    const float* __restrict__ W, float* __restrict__ pp)
{
    __shared__ float At[2][32][132];
    __shared__ float Bt[2][32][132];

    int row0 = blockIdx.x * 128;
    int e0   = blockIdx.y * 128;
    int kb   = blockIdx.z * 128;   // K-quarter base

    bool isx = row0 < (NN * LL0);
    const float* A  = (isx ? x + (size_t)row0 * DD
                           : m + (size_t)(row0 - NN * LL0) * DD) + kb;
    const float* Wp = W + (size_t)e0 * (2 * DD) + (isx ? 0 : DD) + kb;

    int tid = threadIdx.x;
    int sr = tid >> 1;              // staging row 0..127
    int sc = (tid & 1) * 16;        // staging k-offset 0/16
    int ty = tid >> 4, tx = tid & 15;

    const float* Ap = A  + (size_t)sr * DD + sc;
    const float* Bp = Wp + (size_t)sr * (2 * DD) + sc;

    float4 ar[4], br[4];
    #pragma unroll
    for (int i = 0; i < 4; ++i) {
        ar[i] = *(const float4*)(Ap + i * 4);
        br[i] = *(const float4*)(Bp + i * 4);
    }

    float acc[8][8] = {};

    // tile 0 -> buf 0 (transposed; same-k lanes differ only in sr -> conflict-free)
    #pragma unroll
    for (int i = 0; i < 4; ++i) {
        int k = sc + i * 4;
        At[0][k + 0][sr] = ar[i].x; At[0][k + 1][sr] = ar[i].y;
        At[0][k + 2][sr] = ar[i].z; At[0][k + 3][sr] = ar[i].w;
        Bt[0][k + 0][sr] = br[i].x; Bt[0][k + 1][sr] = br[i].y;
        Bt[0][k + 2][sr] = br[i].z; Bt[0][k + 3][sr] = br[i].w;
    }
    __syncthreads();

    for (int kt = 0; kt < 4; ++kt) {
        int cur = kt & 1;
        if (kt < 3) {   // prefetch next K-tile into registers (hides HBM/L2 latency)
            #pragma unroll
            for (int i = 0; i < 4; ++i) {
                ar[i] = *(const float4*)(Ap + (kt + 1) * 32 + i * 4);
                br[i] = *(const float4*)(Bp + (kt + 1) * 32 + i * 4);
            }
        }
        #pragma unroll 4
        for (int kk = 0; kk < 32; ++kk) {
            float4 a0 = *(const float4*)&At[cur][kk][ty * 4];
            float4 a1 = *(const float4*)&At[cur][kk][64 + ty * 4];
            float4 b0 = *(const float4*)&Bt[cur][kk][tx * 4];
            float4 b1 = *(const float4*)&Bt[cur][kk][64 + tx * 4];
            float a_[8] = {a0.x, a0.y, a0.z, a0.w, a1.x, a1.y, a1.z, a1.w};
            float b_[8] = {b0.x, b0.y, b0.z, b0.w, b1.x, b1.y, b1.z, b1.w};
            #pragma unroll
            for (int i = 0; i < 8; ++i)
                #pragma unroll
                for (int j = 0; j < 8; ++j)
                    acc[i][j] = fmaf(a_[i], b_[j], acc[i][j]);
        }
        if (kt < 3) {
            int nxt = cur ^ 1;
            #pragma unroll
            for (int i = 0; i < 4; ++i) {
                int k = sc + i * 4;
                At[nxt][k + 0][sr] = ar[i].x; At[nxt][k + 1][sr] = ar[i].y;
                At[nxt][k + 2][sr] = ar[i].z; At[nxt][k + 3][sr] = ar[i].w;
                Bt[nxt][k + 0][sr] = br[i].x; Bt[nxt][k + 1][sr] = br[i].y;
                Bt[nxt][k + 2][sr] = br[i].z; Bt[nxt][k + 3][sr] = br[i].w;
            }
            __syncthreads();
        }
    }

    float* outp = pp + (size_t)blockIdx.z * PSTR + (size_t)row0 * DD + e0;
    #pragma unroll
    for (int i = 0; i < 8; ++i) {
        int r = (i < 4) ? (ty * 4 + i) : (64 + ty * 4 + (i - 4));
        float4 v0 = make_float4(acc[i][0], acc[i][1], acc[i][2], acc[i][3]);
        float4 v1 = make_float4(acc[i][4], acc[i][5], acc[i][6], acc[i][7]);
        *(float4*)(outp + (size_t)r * DD + tx * 4) = v0;
        *(float4*)(outp + (size_t)r * DD + 64 + tx * 4) = v1;
    }
}

// ---------------------------------------------------------------------------
// Kernel 1b: split-K reduce (4 planes) + bias + LOG2E2 scale.
// ---------------------------------------------------------------------------
__global__ __launch_bounds__(256) void reduce_kernel(
    const float* __restrict__ pp, const float* __restrict__ Wb,
    float* __restrict__ xpb_base)
{
    size_t f = (size_t)blockIdx.x * 256 + threadIdx.x;   // float4 index
    const float4* p4 = (const float4*)pp;
    float4 v0 = p4[f];
    float4 v1 = p4[f + PSTR / 4];
    float4 v2 = p4[f + 2 * (PSTR / 4)];
    float4 v3 = p4[f + 3 * (PSTR / 4)];
    float4 s = make_float4(v0.x + v1.x + v2.x + v3.x,
                           v0.y + v1.y + v2.y + v3.y,
                           v0.z + v1.z + v2.z + v3.z,
                           v0.w + v1.w + v2.w + v3.w);
    size_t off = f * 4;
    if (off < (size_t)NN * LL0 * DD) {   // x-rows: add bias
        float4 wb = *(const float4*)(Wb + (off & (DD - 1)));
        s.x += wb.x; s.y += wb.y; s.z += wb.z; s.w += wb.w;
    }
    s.x *= LOG2E2; s.y *= LOG2E2; s.z *= LOG2E2; s.w *= LOG2E2;
    ((float4*)xpb_base)[f] = s;
}

// ---------------------------------------------------------------------------
// Kernel 2: logits partials, d-chunk = 64.
//   wpart[dc][n][a][b] = sum_{d in chunk dc} V[d] / (2^(xpb[n,a,d]+mp[n,b,d]) + 1)
// Grid (8, 32, 8) = 2048 blocks = 8/CU; LDS 17.7 KB; VGPR capped for 8 waves/EU.
// ---------------------------------------------------------------------------
__global__ __launch_bounds__(256, 8) void logits_kernel(
    const float* __restrict__ xpb, const float* __restrict__ mp,
    const float* __restrict__ Vw,
    float* __restrict__ wpart)
{
    __shared__ __attribute__((aligned(16))) float xs[32][68];
    __shared__ __attribute__((aligned(16))) float ms[32][68];
    __shared__ __attribute__((aligned(16))) float vsh[64];

    int n  = blockIdx.z;
    int bt = blockIdx.x;          // 0..7
    int at = blockIdx.y & 3;      // 0..3
    int dc = blockIdx.y >> 2;     // 0..7 (d-chunk of 64)
    int tid = threadIdx.x;
    int ty = tid >> 4, tx = tid & 15;

    const float* xrow = xpb + (size_t)(n * LL0 + at * 32) * DD + dc * 64;
    const float* mrow = mp  + (size_t)(n * LL1 + bt * 32) * DD + dc * 64;

    {
        int r  = tid >> 3;            // 0..31
        int c8 = (tid & 7) * 8;       // 0..56
        *(float4*)&xs[r][c8]     = *(const float4*)(xrow + (size_t)r * DD + c8);
        *(float4*)&xs[r][c8 + 4] = *(const float4*)(xrow + (size_t)r * DD + c8 + 4);
        *(float4*)&ms[r][c8]     = *(const float4*)(mrow + (size_t)r * DD + c8);
        *(float4*)&ms[r][c8 + 4] = *(const float4*)(mrow + (size_t)r * DD + c8 + 4);
        if (tid < 16)
            *(float4*)&vsh[tid * 4] = *(const float4*)(Vw + dc * 64 + tid * 4);
    }
    __syncthreads();

    float a00 = 0.f, a01 = 0.f, a10 = 0.f, a11 = 0.f;

    #pragma unroll 4
    for (int k4 = 0; k4 < 16; ++k4) {
        float4 xa = *(const float4*)&xs[ty][k4 * 4];
        float4 xb = *(const float4*)&xs[ty + 16][k4 * 4];
        float4 ma = *(const float4*)&ms[tx][k4 * 4];
        float4 mb = *(const float4*)&ms[tx + 16][k4 * 4];
        float4 vv = *(const float4*)&vsh[k4 * 4];

        a00 = fmaf(vv.x, sig2(xa.x + ma.x), a00);
        a00 = fmaf(vv.y, sig2(xa.y + ma.y), a00);
        a00 = fmaf(vv.z, sig2(xa.z + ma.z), a00);
        a00 = fmaf(vv.w, sig2(xa.w + ma.w), a00);

        a01 = fmaf(vv.x, sig2(xa.x + mb.x), a01);
        a01 = fmaf(vv.y, sig2(xa.y + mb.y), a01);
        a01 = fmaf(vv.z, sig2(xa.z + mb.z), a01);
        a01 = fmaf(vv.w, sig2(xa.w + mb.w), a01);

        a10 = fmaf(vv.x, sig2(xb.x + ma.x), a10);
        a10 = fmaf(vv.y, sig2(xb.y + ma.y), a10);
        a10 = fmaf(vv.z, sig2(xb.z + ma.z), a10);
        a10 = fmaf(vv.w, sig2(xb.w + ma.w), a10);

        a11 = fmaf(vv.x, sig2(xb.x + mb.x), a11);
        a11 = fmaf(vv.y, sig2(xb.y + mb.y), a11);
        a11 = fmaf(vv.z, sig2(xb.z + mb.z), a11);
        a11 = fmaf(vv.w, sig2(xb.w + mb.w), a11);
    }

    float* wp = wpart + ((size_t)dc * NN + n) * (size_t)(LL0 * LL1);
    int a = at * 32 + ty;
    int b = bt * 32 + tx;
    wp[(size_t)a * LL1 + b]             = a00;
    wp[(size_t)a * LL1 + b + 16]        = a01;
    wp[(size_t)(a + 16) * LL1 + b]      = a10;
    wp[(size_t)(a + 16) * LL1 + b + 16] = a11;
}

// ---------------------------------------------------------------------------
// Kernel 3: masked softmax over b (sums 8 d-chunk partials, -2 scale).
// ---------------------------------------------------------------------------
__global__ __launch_bounds__(256) void softmax_kernel(
    float* __restrict__ wbuf, const int* __restrict__ mask)
{
    __shared__ float red[4];
    __shared__ float red2[4];
    const size_t P = (size_t)NN * LL0 * LL1;
    int row = blockIdx.x;          // n*L0 + a
    int n = row >> 7;
    int b = threadIdx.x;
    size_t idx = (size_t)row * LL1 + b;

    float s8 = 0.f;
    #pragma unroll
    for (int p = 0; p < 8; ++p) s8 += wbuf[idx + (size_t)p * P];
    float w = -2.0f * s8;
    if (mask[n * LL1 + b] == 0) w = -1e12f;

    float mx = w;
    #pragma unroll
    for (int off = 32; off; off >>= 1) mx = fmaxf(mx, __shfl_xor(mx, off));
    int wv = threadIdx.x >> 6;
    if ((threadIdx.x & 63) == 0) red[wv] = mx;
    __syncthreads();
    mx = fmaxf(fmaxf(red[0], red[1]), fmaxf(red[2], red[3]));

    float e = __expf(w - mx);
    float s = e;
    #pragma unroll
    for (int off = 32; off; off >>= 1) s += __shfl_xor(s, off);
    if ((threadIdx.x & 63) == 0) red2[wv] = s;
    __syncthreads();
    s = red2[0] + red2[1] + red2[2] + red2[3];

    wbuf[idx] = e / s;
}

// ---------------------------------------------------------------------------
// Kernel 4: v[n,a,d] = sum_b w[n,a,b] * m[n,b,d]. (unchanged)
// ---------------------------------------------------------------------------
__global__ __launch_bounds__(256) void vgemm_kernel(
    const float* __restrict__ wbuf, const float* __restrict__ m,
    float* __restrict__ out)
{
    __shared__ float ws_t[64][17];
    __shared__ float ms_t[16][65];

    int n = blockIdx.z;
    int a0 = blockIdx.y * 64;
    int d0 = blockIdx.x * 64;
    int tid = threadIdx.x;
    int ty = tid >> 4, tx = tid & 15;

    const float* wrow = wbuf + ((size_t)n * LL0 + a0) * LL1;
    const float* mrow = m + (size_t)n * LL1 * DD;

    float acc[4][4] = {};
    for (int k0 = 0; k0 < LL1; k0 += 16) {
        {
            int lr = tid >> 2, lc = (tid & 3) * 4;
            float4 wv = *(const float4*)(wrow + (size_t)lr * LL1 + k0 + lc);
            ws_t[lr][lc + 0] = wv.x; ws_t[lr][lc + 1] = wv.y;
            ws_t[lr][lc + 2] = wv.z; ws_t[lr][lc + 3] = wv.w;
        }
        {
            int lr = tid >> 4, lc = (tid & 15) * 4;
            float4 mv = *(const float4*)(mrow + (size_t)(k0 + lr) * DD + d0 + lc);
            ms_t[lr][lc + 0] = mv.x; ms_t[lr][lc + 1] = mv.y;
            ms_t[lr][lc + 2] = mv.z; ms_t[lr][lc + 3] = mv.w;
        }
        __syncthreads();
        #pragma unroll
        for (int kk = 0; kk < 16; ++kk) {
            float a_[4], b_[4];
            #pragma unroll
            for (int i = 0; i < 4; ++i) a_[i] = ws_t[ty * 4 + i][kk];
            #pragma unroll
            for (int j = 0; j < 4; ++j) b_[j] = ms_t[kk][tx * 4 + j];
            #pragma unroll
            for (int i = 0; i < 4; ++i)
                #pragma unroll
                for (int j = 0; j < 4; ++j)
                    acc[i][j] = fmaf(a_[i], b_[j], acc[i][j]);
        }
        __syncthreads();
    }
    #pragma unroll
    for (int i = 0; i < 4; ++i)
        #pragma unroll
        for (int j = 0; j < 4; ++j)
            out[((size_t)n * LL0 + a0 + ty * 4 + i) * DD + d0 + tx * 4 + j] = acc[i][j];
}

extern "C" void kernel_launch(void* const* d_in, const int* in_sizes, int n_in,
                              void* d_out, int out_size, void* d_ws, size_t ws_size,
                              hipStream_t stream) {
    const float* x    = (const float*)d_in[0];
    const float* m    = (const float*)d_in[1];
    const int*   mask = (const int*)d_in[2];
    const float* W_w  = (const float*)d_in[3];
    const float* W_b  = (const float*)d_in[4];
    const float* V_w  = (const float*)d_in[5];
    const float* V_b  = (const float*)d_in[6];
    (void)V_b; // additive constant — cancels under softmax shift-invariance
    float* out = (float*)d_out;

    // Workspace layout (floats):
    //   xpb    : 8*128*512           =  524288
    //   mp     : 8*256*512           = 1048576   (contiguous after xpb)
    //   region : max(pp 4*3072*512 = 6291456, wpart 8*8*128*256 = 2097152)
    // pp (split-K partials) is dead after reduce_kernel; wpart aliases it.
    // Total: 7,864,320 floats = 31.5 MB
    float* xpb    = (float*)d_ws;
    float* mp     = xpb + (size_t)NN * LL0 * DD;
    float* region = mp + (size_t)NN * LL1 * DD;
    float* pp     = region;
    float* wpart  = region;

    proj_kernel<<<dim3(24, 4, 4), 256, 0, stream>>>(x, m, W_w, pp);
    reduce_kernel<<<dim3(1536), 256, 0, stream>>>(pp, W_b, xpb);
    logits_kernel<<<dim3(8, 32, 8), 256, 0, stream>>>(xpb, mp, V_w, wpart);
    softmax_kernel<<<dim3(1024), 256, 0, stream>>>(wpart, mask);
    vgemm_kernel<<<dim3(8, 2, 8), 256, 0, stream>>>(wpart, m, out);
}